// Round 17
// baseline (222.267 us; speedup 1.0000x reference)
//
#include <hip/hip_runtime.h>
#include <hip/hip_bf16.h>

#define HIDDEN 128
#define NHEAD  8
#define DHEAD  16
#define KBLK   64
#define QPB    2      // q-tiles (64 rows) per block -> 128 q rows/block
#define TILEB  4096   // staged bytes per keytile: K f16 2K | vT f16 2K
#define QSCALE 5.77078016355585277626f   // sqrt(d_head)*log2(e): softmax in log2 domain

typedef __attribute__((ext_vector_type(8))) _Float16 f16x8;
typedef __attribute__((ext_vector_type(4))) _Float16 f16x4;
typedef __attribute__((ext_vector_type(4))) float  f32x4;
typedef __attribute__((ext_vector_type(2))) float  f32x2;
typedef __attribute__((ext_vector_type(4))) int    i32x4;

// Key permutation [verified r6-r16]: key k stored at QK-A-tile (sub,irow) so the
// QK C-output s[sub][r] in lane (g,lr) is exactly PV-A-operand slot g*8+sub*4+r.
__device__ __forceinline__ int ksub(int k)  { return ((k >> 5) << 1) | ((k >> 2) & 1); }
__device__ __forceinline__ int kirow(int k) { return (((k >> 3) & 3) << 2) | (k & 3); }

// Stg tile layout (fp16):
//   [0,2048):    K  [sub4][half2(dims0-7|8-15)][row16][16B], row = kirow(k)
//   [2048,4096): V^T rows d=0..15 x 128B, 16B granules XOR-swizzled by ((d&7)<<4)
__device__ __forceinline__ void cvt_store(char* Sb, int ka, i32x4 vaddr,
                                          f32x4 kvec, f32x4 vvec)
{
    f16x4 kh;
    #pragma unroll
    for (int i = 0; i < 4; ++i) kh[i] = (_Float16)kvec[i];
    *(f16x4*)(Sb + ka) = kh;
    #pragma unroll
    for (int i = 0; i < 4; ++i)
        *(_Float16*)(Sb + vaddr[i]) = (_Float16)vvec[i];
}

template<bool SPLIT>
__global__ __launch_bounds__(256, 4)
void mha_fwd(const float* __restrict__ kv,
             const float* __restrict__ q,
             const int*   __restrict__ seq_len,
             float* __restrict__ out,
             _Float16* __restrict__ pbuf,       // SPLIT: [row][16] f16
             float* __restrict__ mlbuf,         // SPLIT: [row][2] f32
             unsigned* __restrict__ cnt,        // SPLIT: per-(b,h,qpair) counters
             int S, int nc, int chunk)
{
    const int qpair = blockIdx.x;
    const int h     = blockIdx.y;
    int b, c0, Bn;
    if (SPLIT) { Bn = gridDim.z / nc; b = blockIdx.z % Bn; c0 = blockIdx.z / Bn; }
    else       { b = blockIdx.z; c0 = 0; Bn = gridDim.z; }
    const int L = seq_len[b];
    const int kstart = SPLIT ? c0 * chunk : 0;
    if (SPLIT && kstart >= L) return;              // block-uniform exit, before any barrier
    const int kend = SPLIT ? min(L, kstart + chunk) : L;

    const int tid  = threadIdx.x;
    const int lane = tid & 63;
    const int wave = tid >> 6;
    const int g    = lane >> 4;
    const int lr   = lane & 15;
    const int sw   = (lr & 7) << 4;

    __shared__ __align__(16) char Stg[2][TILEB];

    // ---- Q fragments (fp16 hi/lo pair -> exact Q): slots 0-15 Q_hi, 16-31 Q_lo ----
    const int qrowb = qpair * (QPB * KBLK) + wave * 16 + lr;
    f16x8 qf[QPB];
    #pragma unroll
    for (int qt = 0; qt < QPB; ++qt) {
        const float* qp = q + ((size_t)(b * S + qrowb + qt * KBLK) * HIDDEN) + h * DHEAD + (g & 1) * 8;
        #pragma unroll
        for (int j = 0; j < 8; ++j) {
            float qv = qp[j] * QSCALE;
            _Float16 hi = (_Float16)qv;
            qf[qt][j] = (g < 2) ? hi : (_Float16)(qv - (float)hi);
        }
    }

    // ---- staging assignment: thread = (key sk, dim-quarter qd) ----
    const int sk = tid >> 2;
    const int qd = tid & 3;
    const float* kvp = kv + ((size_t)(b * S + sk) * (2 * HIDDEN)) + h * DHEAD + 4 * qd;
    const int ka = ksub(sk) * 512 + (qd >> 1) * 256 + kirow(sk) * 16 + (qd & 1) * 8;
    i32x4 vaddr;
    #pragma unroll
    for (int i = 0; i < 4; ++i) {
        const int d = 4 * qd + i;
        vaddr[i] = 2048 + d * 128 + (((sk >> 3) * 16) ^ ((d & 7) << 4)) + (sk & 7) * 2;
    }

    f32x4 acc[QPB];
    float m[QPB], lsum[QPB];                    // lsum = per-lane partial (16 keys)
    #pragma unroll
    for (int qt = 0; qt < QPB; ++qt) {
        acc[qt] = (f32x4){0.f, 0.f, 0.f, 0.f};
        m[qt] = -1e30f; lsum[qt] = 0.f;
    }

    const int ntiles = (kend - kstart + KBLK - 1) >> 6;

    // ---- prologue: stage tile 0 ----
    {
        const float* kp = kvp + (size_t)kstart * (2 * HIDDEN);
        f32x4 kvec = *(const f32x4*)kp;
        f32x4 vvec = *(const f32x4*)(kp + HIDDEN);
        cvt_store(&Stg[0][0], ka, vaddr, kvec, vvec);
    }
    __syncthreads();

    for (int ti = 0; ti < ntiles; ++ti) {
        const int kb = kstart + ti * KBLK;
        const char* Sb = &Stg[ti & 1][0];
        const bool hasnext = (ti + 1) < ntiles;

        // ---- T14: issue next tile's global loads before compute ----
        f32x4 nkv, nvv;
        if (hasnext) {
            const float* kp = kvp + (size_t)(kb + KBLK) * (2 * HIDDEN);
            nkv = *(const f32x4*)kp;
            nvv = *(const f32x4*)(kp + HIDDEN);
        }

        // ---- K/V fragments: read once, reused by both q-streams ----
        f16x8 kf[4];
        #pragma unroll
        for (int sub = 0; sub < 4; ++sub)
            kf[sub] = *(const f16x8*)(Sb + sub * 512 + (g & 1) * 256 + lr * 16);
        f16x8 vb0 = *(const f16x8*)(Sb + 2048 + lr * 128 + ((g * 16) ^ sw));
        f16x8 vb1 = *(const f16x8*)(Sb + 2048 + lr * 128 + ((64 + g * 16) ^ sw));

        const bool bnd = (kb + KBLK > kend);

        // ---- phase 1: QK^T for BOTH q-streams (8 independent MFMAs) ----
        f32x4 s[QPB][4];
        __builtin_amdgcn_s_setprio(1);
        #pragma unroll
        for (int qt = 0; qt < QPB; ++qt)
            #pragma unroll
            for (int sub = 0; sub < 4; ++sub) {
                f32x4 z = {0.f, 0.f, 0.f, 0.f};
                s[qt][sub] = __builtin_amdgcn_mfma_f32_16x16x32_f16(kf[sub], qf[qt], z, 0, 0, 0);
            }
        __builtin_amdgcn_s_setprio(0);

        if (bnd) {
            #pragma unroll
            for (int qt = 0; qt < QPB; ++qt)
                #pragma unroll
                for (int sub = 0; sub < 4; ++sub) {
                    const int kb2 = kb + (sub >> 1) * 32 + (sub & 1) * 4 + g * 8;
                    #pragma unroll
                    for (int r = 0; r < 4; ++r)
                        if (kb2 + r >= kend) s[qt][sub][r] = -1e30f;
                }
        }

        // ---- phase 2: softmax for BOTH streams (independent chains interleave) ----
        f16x8 pa[QPB][2];
        #pragma unroll
        for (int qt = 0; qt < QPB; ++qt) {
            float t0 = fmaxf(fmaxf(s[qt][0][0], s[qt][0][1]), fmaxf(s[qt][0][2], s[qt][0][3]));
            float t1 = fmaxf(fmaxf(s[qt][1][0], s[qt][1][1]), fmaxf(s[qt][1][2], s[qt][1][3]));
            float t2 = fmaxf(fmaxf(s[qt][2][0], s[qt][2][1]), fmaxf(s[qt][2][2], s[qt][2][3]));
            float t3 = fmaxf(fmaxf(s[qt][3][0], s[qt][3][1]), fmaxf(s[qt][3][2], s[qt][3][3]));
            float tmax = fmaxf(fmaxf(t0, t1), fmaxf(t2, t3));
            tmax = fmaxf(tmax, __shfl_xor(tmax, 16));
            tmax = fmaxf(tmax, __shfl_xor(tmax, 32));

            const float mn = fmaxf(m[qt], tmax);
            const float alpha = exp2f(m[qt] - mn);
            m[qt] = mn;

            float rsum = 0.f;
            #pragma unroll
            for (int sub = 0; sub < 4; ++sub)
                #pragma unroll
                for (int r = 0; r < 4; ++r) {
                    float p = exp2f(s[qt][sub][r] - mn);
                    rsum += p;
                    pa[qt][sub >> 1][(sub & 1) * 4 + r] = (_Float16)p;
                }
            lsum[qt] = lsum[qt] * alpha + rsum;   // per-lane; reduced once in epilogue
            acc[qt] *= alpha;
        }

        // ---- phase 3: PV for BOTH streams ----
        __builtin_amdgcn_s_setprio(1);
        #pragma unroll
        for (int qt = 0; qt < QPB; ++qt) {
            acc[qt] = __builtin_amdgcn_mfma_f32_16x16x32_f16(vb0, pa[qt][0], acc[qt], 0, 0, 0);
            acc[qt] = __builtin_amdgcn_mfma_f32_16x16x32_f16(vb1, pa[qt][1], acc[qt], 0, 0, 0);
        }
        __builtin_amdgcn_s_setprio(0);

        // ---- T14 completion: convert + ds_write next tile, then one barrier ----
        if (hasnext)
            cvt_store(&Stg[(ti + 1) & 1][0], ka, vaddr, nkv, nvv);
        __syncthreads();
    }

    // ---- epilogue: lsum reduce once; store (m, lsum in base-2 units) ----
    #pragma unroll
    for (int qt = 0; qt < QPB; ++qt) {
        lsum[qt] += __shfl_xor(lsum[qt], 16);
        lsum[qt] += __shfl_xor(lsum[qt], 32);
        const int qglob = qrowb + qt * KBLK;
        if (SPLIT) {
            const size_t row = (((size_t)b * nc + c0) * S + qglob) * NHEAD + h;
            f16x4 pk;
            #pragma unroll
            for (int r = 0; r < 4; ++r) pk[r] = (_Float16)acc[qt][r];
            *(f16x4*)&pbuf[row * DHEAD + g * 4] = pk;
            if (g == 0) { f32x2 ml = {m[qt], lsum[qt]}; *(f32x2*)&mlbuf[row * 2] = ml; }
        } else {
            const float inv = 1.0f / lsum[qt];
            *(f32x4*)&out[((size_t)b * S + qglob) * HIDDEN + h * DHEAD + g * 4] = acc[qt] * inv;
        }
    }

    // ---- fused split-K merge: last finishing chunk-block merges the group ----
    if (SPLIT) {
        __threadfence();                           // release: partials visible device-wide
        __shared__ unsigned s_old;
        const int grp = ((b * NHEAD) + h) * gridDim.x + qpair;
        if (tid == 0) s_old = atomicAdd(&cnt[grp], 1u);
        __syncthreads();
        const int nvalid = min(nc, (L + chunk - 1) / chunk);
        if ((int)s_old == nvalid - 1) {
            __threadfence();                       // acquire: see all chunks' partials
            // 256 threads merge 128 rows x 16 dims: row = tid>>1, 8-dim half = tid&1
            const int r  = tid >> 1;
            const int hf = tid & 1;
            const int qg = qpair * (QPB * KBLK) + r;
            const size_t cstr = (size_t)S * NHEAD;
            const size_t row0 = ((size_t)b * nc) * cstr + (size_t)qg * NHEAD + h;
            float M = -1e30f;
            for (int c = 0; c < nvalid; ++c)
                M = fmaxf(M, mlbuf[(row0 + c * cstr) * 2]);
            float den = 0.f;
            float o[8];
            #pragma unroll
            for (int i = 0; i < 8; ++i) o[i] = 0.f;
            for (int c = 0; c < nvalid; ++c) {
                f32x2 ml = *(const f32x2*)&mlbuf[(row0 + c * cstr) * 2];
                const float w = exp2f(ml[0] - M);  // base-2 m
                den += w * ml[1];
                f16x8 p = *(const f16x8*)&pbuf[(row0 + c * cstr) * DHEAD + hf * 8];
                #pragma unroll
                for (int i = 0; i < 8; ++i) o[i] += w * (float)p[i];
            }
            const float inv = 1.0f / den;
            float* op = &out[((size_t)b * S + qg) * HIDDEN + h * DHEAD + hf * 8];
            #pragma unroll
            for (int i = 0; i < 2; ++i) {
                f32x4 v = {o[4*i] * inv, o[4*i+1] * inv, o[4*i+2] * inv, o[4*i+3] * inv};
                *(f32x4*)&op[4 * i] = v;
            }
        }
    }
}

extern "C" void kernel_launch(void* const* d_in, const int* in_sizes, int n_in,
                              void* d_out, int out_size, void* d_ws, size_t ws_size,
                              hipStream_t stream)
{
    const float* kv      = (const float*)d_in[0];
    const float* query   = (const float*)d_in[1];
    const int*   seq_len = (const int*)d_in[2];
    float* out           = (float*)d_out;

    const int B = in_sizes[2];
    const int S = in_sizes[1] / (B * HIDDEN);
    const int QP = S / (QPB * KBLK);

    const int chunk = 512;
    const int nc = (S + chunk - 1) / chunk;
    const int ngroups = B * NHEAD * QP;
    const size_t cntb = ((size_t)ngroups * sizeof(unsigned) + 255) & ~(size_t)255;
    const size_t mlb  = (size_t)B * nc * S * NHEAD * 2 * sizeof(float);
    const size_t pbb  = (size_t)B * nc * S * NHEAD * DHEAD * sizeof(_Float16);

    if (nc <= 8 && ws_size >= cntb + mlb + pbb) {
        unsigned* cnt  = (unsigned*)d_ws;
        float* mlbuf   = (float*)((char*)d_ws + cntb);
        _Float16* pbuf = (_Float16*)((char*)d_ws + cntb + mlb);
        hipMemsetAsync(d_ws, 0, cntb, stream);
        mha_fwd<true><<<dim3(QP, NHEAD, B * nc), dim3(256), 0, stream>>>(
            kv, query, seq_len, out, pbuf, mlbuf, cnt, S, nc, chunk);
    } else {
        mha_fwd<false><<<dim3(QP, NHEAD, B), dim3(256), 0, stream>>>(
            kv, query, seq_len, out, nullptr, nullptr, nullptr, S, 1, S);
    }
}

// Round 18
// 40.519 us; speedup vs baseline: 5.4855x; 5.4855x over previous
//
#include <hip/hip_runtime.h>
#include <hip/hip_bf16.h>

#define HIDDEN 128
#define NHEAD  8
#define DHEAD  16
#define KBLK   64
#define QPB    2      // q-tiles (64 rows) per block -> 128 q rows/block
#define TILEB  4096   // staged bytes per keytile: K f16 2K | vT f16 2K
#define QSCALE 5.77078016355585277626f   // sqrt(d_head)*log2(e): softmax in log2 domain
#define RTHR   8.0f   // defer-max threshold (log2 units)

typedef __attribute__((ext_vector_type(8))) _Float16 f16x8;
typedef __attribute__((ext_vector_type(4))) _Float16 f16x4;
typedef __attribute__((ext_vector_type(4))) float  f32x4;
typedef __attribute__((ext_vector_type(2))) float  f32x2;
typedef __attribute__((ext_vector_type(4))) int    i32x4;

// Key permutation [verified r6-r16]: key k stored at QK-A-tile (sub,irow) so the
// QK C-output s[sub][r] in lane (g,lr) is exactly PV-A-operand slot g*8+sub*4+r.
__device__ __forceinline__ int ksub(int k)  { return ((k >> 5) << 1) | ((k >> 2) & 1); }
__device__ __forceinline__ int kirow(int k) { return (((k >> 3) & 3) << 2) | (k & 3); }

// Stg tile layout (fp16):
//   [0,2048):    K  [sub4][half2(dims0-7|8-15)][row16][16B], row = kirow(k)
//   [2048,4096): V^T rows d=0..15 x 128B, 16B granules XOR-swizzled by ((d&7)<<4)
__device__ __forceinline__ void cvt_store(char* Sb, int ka, i32x4 vaddr,
                                          f32x4 kvec, f32x4 vvec)
{
    f16x4 kh;
    #pragma unroll
    for (int i = 0; i < 4; ++i) kh[i] = (_Float16)kvec[i];
    *(f16x4*)(Sb + ka) = kh;
    #pragma unroll
    for (int i = 0; i < 4; ++i)
        *(_Float16*)(Sb + vaddr[i]) = (_Float16)vvec[i];
}

template<bool SPLIT>
__global__ __launch_bounds__(256, 4)
void mha_fwd(const float* __restrict__ kv,
             const float* __restrict__ q,
             const int*   __restrict__ seq_len,
             float* __restrict__ out,           // !SPLIT
             _Float16* __restrict__ pbuf,       // SPLIT: [row][16] f16, NORMALIZED per-chunk out
             float* __restrict__ mlbuf,         // SPLIT: [row][2] f32 = (m, lsum)
             int S, int nc, int chunk)
{
    const int qpair = blockIdx.x;
    const int h     = blockIdx.y;
    int b, c0;
    if (SPLIT) { const int Bn = gridDim.z / nc; b = blockIdx.z % Bn; c0 = blockIdx.z / Bn; }
    else       { b = blockIdx.z; c0 = 0; }
    const int L = seq_len[b];
    const int kstart = SPLIT ? c0 * chunk : 0;
    if (SPLIT && kstart >= L) return;              // block-uniform exit, before any barrier
    const int kend = SPLIT ? min(L, kstart + chunk) : L;

    const int tid  = threadIdx.x;
    const int lane = tid & 63;
    const int wave = tid >> 6;
    const int g    = lane >> 4;
    const int lr   = lane & 15;
    const int sw   = (lr & 7) << 4;

    __shared__ __align__(16) char Stg[2][TILEB];

    // ---- Q fragments (fp16 hi/lo pair -> exact Q): slots 0-15 Q_hi, 16-31 Q_lo ----
    const int qrowb = qpair * (QPB * KBLK) + wave * 16 + lr;
    f16x8 qf[QPB];
    #pragma unroll
    for (int qt = 0; qt < QPB; ++qt) {
        const float* qp = q + ((size_t)(b * S + qrowb + qt * KBLK) * HIDDEN) + h * DHEAD + (g & 1) * 8;
        #pragma unroll
        for (int j = 0; j < 8; ++j) {
            float qv = qp[j] * QSCALE;
            _Float16 hi = (_Float16)qv;
            qf[qt][j] = (g < 2) ? hi : (_Float16)(qv - (float)hi);
        }
    }

    // ---- staging assignment: thread = (key sk, dim-quarter qd) ----
    const int sk = tid >> 2;
    const int qd = tid & 3;
    const float* kvp = kv + ((size_t)(b * S + sk) * (2 * HIDDEN)) + h * DHEAD + 4 * qd;
    const int ka = ksub(sk) * 512 + (qd >> 1) * 256 + kirow(sk) * 16 + (qd & 1) * 8;
    i32x4 vaddr;
    #pragma unroll
    for (int i = 0; i < 4; ++i) {
        const int d = 4 * qd + i;
        vaddr[i] = 2048 + d * 128 + (((sk >> 3) * 16) ^ ((d & 7) << 4)) + (sk & 7) * 2;
    }

    f32x4 acc[QPB];
    float m[QPB], lsum[QPB];                    // per-lane partials (16 keys)
    #pragma unroll
    for (int qt = 0; qt < QPB; ++qt) {
        acc[qt] = (f32x4){0.f, 0.f, 0.f, 0.f};
        m[qt] = -1e30f; lsum[qt] = 0.f;
    }

    const int ntiles = (kend - kstart + KBLK - 1) >> 6;

    // ---- prologue: stage tile 0 ----
    {
        const float* kp = kvp + (size_t)kstart * (2 * HIDDEN);
        f32x4 kvec = *(const f32x4*)kp;
        f32x4 vvec = *(const f32x4*)(kp + HIDDEN);
        cvt_store(&Stg[0][0], ka, vaddr, kvec, vvec);
    }
    __syncthreads();

    for (int ti = 0; ti < ntiles; ++ti) {
        const int kb = kstart + ti * KBLK;
        const char* Sb = &Stg[ti & 1][0];
        const bool hasnext = (ti + 1) < ntiles;

        // ---- T14: issue next tile's global loads before compute ----
        f32x4 nkv, nvv;
        if (hasnext) {
            const float* kp = kvp + (size_t)(kb + KBLK) * (2 * HIDDEN);
            nkv = *(const f32x4*)kp;
            nvv = *(const f32x4*)(kp + HIDDEN);
        }

        // ---- K/V fragments: read once, reused by both q-streams ----
        f16x8 kf[4];
        #pragma unroll
        for (int sub = 0; sub < 4; ++sub)
            kf[sub] = *(const f16x8*)(Sb + sub * 512 + (g & 1) * 256 + lr * 16);
        f16x8 vb0 = *(const f16x8*)(Sb + 2048 + lr * 128 + ((g * 16) ^ sw));
        f16x8 vb1 = *(const f16x8*)(Sb + 2048 + lr * 128 + ((64 + g * 16) ^ sw));

        const bool bnd = (kb + KBLK > kend);

        // ---- phase 1: QK^T for BOTH q-streams (8 independent MFMAs) ----
        // swapped+permuted: A slots [k|k], B slots [qh|ql] -> s = k*(qh+ql)
        f32x4 s[QPB][4];
        __builtin_amdgcn_s_setprio(1);
        #pragma unroll
        for (int qt = 0; qt < QPB; ++qt)
            #pragma unroll
            for (int sub = 0; sub < 4; ++sub) {
                f32x4 z = {0.f, 0.f, 0.f, 0.f};
                s[qt][sub] = __builtin_amdgcn_mfma_f32_16x16x32_f16(kf[sub], qf[qt], z, 0, 0, 0);
            }
        __builtin_amdgcn_s_setprio(0);

        if (bnd) {
            #pragma unroll
            for (int qt = 0; qt < QPB; ++qt)
                #pragma unroll
                for (int sub = 0; sub < 4; ++sub) {
                    const int kb2 = kb + (sub >> 1) * 32 + (sub & 1) * 4 + g * 8;
                    #pragma unroll
                    for (int r = 0; r < 4; ++r)
                        if (kb2 + r >= kend) s[qt][sub][r] = -1e30f;
                }
        }

        // ---- phase 2: softmax for BOTH streams; T13 defer-max ----
        f16x8 pa[QPB][2];
        #pragma unroll
        for (int qt = 0; qt < QPB; ++qt) {
            float t0 = fmaxf(fmaxf(s[qt][0][0], s[qt][0][1]), fmaxf(s[qt][0][2], s[qt][0][3]));
            float t1 = fmaxf(fmaxf(s[qt][1][0], s[qt][1][1]), fmaxf(s[qt][1][2], s[qt][1][3]));
            float t2 = fmaxf(fmaxf(s[qt][2][0], s[qt][2][1]), fmaxf(s[qt][2][2], s[qt][2][3]));
            float t3 = fmaxf(fmaxf(s[qt][3][0], s[qt][3][1]), fmaxf(s[qt][3][2], s[qt][3][3]));
            float pmax = fmaxf(fmaxf(t0, t1), fmaxf(t2, t3));

            if (__any(pmax > m[qt] + RTHR)) {       // rare after first tile
                float tmax = fmaxf(pmax, __shfl_xor(pmax, 16));
                tmax = fmaxf(tmax, __shfl_xor(tmax, 32));
                const float mn2 = fmaxf(m[qt], tmax);
                const float alpha = exp2f(m[qt] - mn2);
                m[qt] = mn2;
                lsum[qt] *= alpha;
                acc[qt] *= alpha;
            }
            const float mn = m[qt];

            float rsum = 0.f;
            #pragma unroll
            for (int sub = 0; sub < 4; ++sub)
                #pragma unroll
                for (int r = 0; r < 4; ++r) {
                    float p = exp2f(s[qt][sub][r] - mn);
                    rsum += p;
                    pa[qt][sub >> 1][(sub & 1) * 4 + r] = (_Float16)p;
                }
            lsum[qt] += rsum;                       // per-lane; reduced in epilogue
        }

        // ---- T14 completion EARLY: ds_writes issue under the PV MFMAs ----
        if (hasnext)
            cvt_store(&Stg[(ti + 1) & 1][0], ka, vaddr, nkv, nvv);

        // ---- phase 3: PV for BOTH streams ----
        __builtin_amdgcn_s_setprio(1);
        #pragma unroll
        for (int qt = 0; qt < QPB; ++qt) {
            acc[qt] = __builtin_amdgcn_mfma_f32_16x16x32_f16(vb0, pa[qt][0], acc[qt], 0, 0, 0);
            acc[qt] = __builtin_amdgcn_mfma_f32_16x16x32_f16(vb1, pa[qt][1], acc[qt], 0, 0, 0);
        }
        __builtin_amdgcn_s_setprio(0);

        __syncthreads();
    }

    // ---- epilogue: lsum reduce once; store NORMALIZED output ----
    #pragma unroll
    for (int qt = 0; qt < QPB; ++qt) {
        lsum[qt] += __shfl_xor(lsum[qt], 16);
        lsum[qt] += __shfl_xor(lsum[qt], 32);
        const float inv = 1.0f / lsum[qt];
        const int qglob = qrowb + qt * KBLK;
        if (SPLIT) {
            const size_t row = (((size_t)b * nc + c0) * S + qglob) * NHEAD + h;
            f16x4 pk;
            #pragma unroll
            for (int r = 0; r < 4; ++r) pk[r] = (_Float16)(acc[qt][r] * inv);
            *(f16x4*)&pbuf[row * DHEAD + g * 4] = pk;
            if (g == 0) { f32x2 ml = {m[qt], lsum[qt]}; *(f32x2*)&mlbuf[row * 2] = ml; }
        } else {
            *(f32x4*)&out[((size_t)b * S + qglob) * HIDDEN + h * DHEAD + g * 4] = acc[qt] * inv;
        }
    }
}

__global__ __launch_bounds__(256)
void mha_merge(const _Float16* __restrict__ pbuf, const float* __restrict__ mlbuf,
               const int* __restrict__ seq_len, float* __restrict__ out,
               int S, int nc, int chunk)
{
    const int t = blockIdx.x * 256 + threadIdx.x;   // (b, q, h), h fastest
    const int h = t & (NHEAD - 1);
    const int rest = t >> 3;
    const int qg = rest % S;
    const int b  = rest / S;
    const int L  = seq_len[b];
    const int nch = min(nc, (L + chunk - 1) / chunk);

    const size_t cstr = (size_t)S * NHEAD;
    const size_t row0 = ((size_t)b * nc) * cstr + (size_t)qg * NHEAD + h;

    float mv[8], lv[8];
    float M = -1e30f;
    for (int c = 0; c < nch; ++c) {
        f32x2 ml = *(const f32x2*)&mlbuf[(row0 + c * cstr) * 2];
        mv[c] = ml[0]; lv[c] = ml[1];
        M = fmaxf(M, ml[0]);
    }
    float den = 0.f;
    float o[16];
    #pragma unroll
    for (int i = 0; i < 16; ++i) o[i] = 0.f;
    for (int c = 0; c < nch; ++c) {
        const float wl = exp2f(mv[c] - M) * lv[c];  // weight for NORMALIZED partials
        den += wl;
        const _Float16* pp = &pbuf[(row0 + c * cstr) * DHEAD];
        f16x8 p0 = *(const f16x8*)&pp[0];
        f16x8 p1 = *(const f16x8*)&pp[8];
        #pragma unroll
        for (int i = 0; i < 8; ++i) {
            o[i]     += wl * (float)p0[i];
            o[i + 8] += wl * (float)p1[i];
        }
    }
    const float inv = 1.0f / den;
    float* op = &out[((size_t)b * S + qg) * HIDDEN + h * DHEAD];
    #pragma unroll
    for (int i = 0; i < 4; ++i) {
        f32x4 v = {o[4*i] * inv, o[4*i+1] * inv, o[4*i+2] * inv, o[4*i+3] * inv};
        *(f32x4*)&op[4 * i] = v;
    }
}

extern "C" void kernel_launch(void* const* d_in, const int* in_sizes, int n_in,
                              void* d_out, int out_size, void* d_ws, size_t ws_size,
                              hipStream_t stream)
{
    const float* kv      = (const float*)d_in[0];
    const float* query   = (const float*)d_in[1];
    const int*   seq_len = (const int*)d_in[2];
    float* out           = (float*)d_out;

    const int B = in_sizes[2];
    const int S = in_sizes[1] / (B * HIDDEN);

    const int chunk = 512;
    const int nc = (S + chunk - 1) / chunk;
    const size_t mlb = (size_t)B * nc * S * NHEAD * 2 * sizeof(float);
    const size_t pbb = (size_t)B * nc * S * NHEAD * DHEAD * sizeof(_Float16);

    if (nc <= 8 && ws_size >= mlb + pbb) {
        float* mlbuf = (float*)d_ws;
        _Float16* pbuf = (_Float16*)((char*)d_ws + mlb);
        mha_fwd<true><<<dim3(S / (QPB * KBLK), NHEAD, B * nc), dim3(256), 0, stream>>>(
            kv, query, seq_len, nullptr, pbuf, mlbuf, S, nc, chunk);
        const int nrows = B * S * NHEAD;
        mha_merge<<<dim3((nrows + 255) / 256), dim3(256), 0, stream>>>(
            pbuf, mlbuf, seq_len, out, S, nc, chunk);
    } else {
        mha_fwd<false><<<dim3(S / (QPB * KBLK), NHEAD, B), dim3(256), 0, stream>>>(
            kv, query, seq_len, out, nullptr, nullptr, S, 1, S);
    }
}

// Round 19
// 38.535 us; speedup vs baseline: 5.7679x; 1.0515x over previous
//
#include <hip/hip_runtime.h>
#include <hip/hip_bf16.h>

#define HIDDEN 128
#define NHEAD  8
#define DHEAD  16
#define KBLK   64
#define QPB    2      // q-tiles (64 rows) per block -> 128 q rows/block
#define TILEB  4096   // staged bytes per keytile: K f16 2K | vT f16 2K
#define QSCALE 5.77078016355585277626f   // sqrt(d_head)*log2(e): softmax in log2 domain

typedef __attribute__((ext_vector_type(8))) _Float16 f16x8;
typedef __attribute__((ext_vector_type(4))) _Float16 f16x4;
typedef __attribute__((ext_vector_type(4))) float  f32x4;
typedef __attribute__((ext_vector_type(2))) float  f32x2;
typedef __attribute__((ext_vector_type(4))) int    i32x4;

// Key permutation [verified r6-r18]: key k stored at QK-A-tile (sub,irow) so the
// QK C-output s[sub][r] in lane (g,lr) is exactly PV-A-operand slot g*8+sub*4+r.
__device__ __forceinline__ int ksub(int k)  { return ((k >> 5) << 1) | ((k >> 2) & 1); }
__device__ __forceinline__ int kirow(int k) { return (((k >> 3) & 3) << 2) | (k & 3); }

// Stg tile layout (fp16):
//   [0,2048):    K  [sub4][half2(dims0-7|8-15)][row16][16B], row = kirow(k)
//   [2048,4096): V^T rows d=0..15 x 128B, 16B granules XOR-swizzled by ((d&7)<<4)
__device__ __forceinline__ void cvt_store(char* Sb, int ka, i32x4 vaddr,
                                          f32x4 kvec, f32x4 vvec)
{
    f16x4 kh;
    #pragma unroll
    for (int i = 0; i < 4; ++i) kh[i] = (_Float16)kvec[i];
    *(f16x4*)(Sb + ka) = kh;
    #pragma unroll
    for (int i = 0; i < 4; ++i)
        *(_Float16*)(Sb + vaddr[i]) = (_Float16)vvec[i];
}

template<bool SPLIT>
__global__ __launch_bounds__(256, 4)
void mha_fwd(const float* __restrict__ kv,
             const float* __restrict__ q,
             const int*   __restrict__ seq_len,
             float* __restrict__ out,           // !SPLIT
             _Float16* __restrict__ pbuf,       // SPLIT: [row][16] f16
             float* __restrict__ mlbuf,         // SPLIT: [row][2] f32
             int S, int nc, int chunk)
{
    const int qpair = blockIdx.x;
    const int h     = blockIdx.y;
    int b, c0;
    if (SPLIT) { const int Bn = gridDim.z / nc; b = blockIdx.z % Bn; c0 = blockIdx.z / Bn; }
    else       { b = blockIdx.z; c0 = 0; }
    const int L = seq_len[b];
    const int kstart = SPLIT ? c0 * chunk : 0;
    if (SPLIT && kstart >= L) return;              // block-uniform exit, before any barrier
    const int kend = SPLIT ? min(L, kstart + chunk) : L;

    const int tid  = threadIdx.x;
    const int lane = tid & 63;
    const int wave = tid >> 6;
    const int g    = lane >> 4;
    const int lr   = lane & 15;
    const int sw   = (lr & 7) << 4;

    __shared__ __align__(16) char Stg[2][TILEB];

    // ---- Q fragments (fp16 hi/lo pair -> exact Q): slots 0-15 Q_hi, 16-31 Q_lo ----
    const int qrowb = qpair * (QPB * KBLK) + wave * 16 + lr;
    f16x8 qf[QPB];
    #pragma unroll
    for (int qt = 0; qt < QPB; ++qt) {
        const float* qp = q + ((size_t)(b * S + qrowb + qt * KBLK) * HIDDEN) + h * DHEAD + (g & 1) * 8;
        #pragma unroll
        for (int j = 0; j < 8; ++j) {
            float qv = qp[j] * QSCALE;
            _Float16 hi = (_Float16)qv;
            qf[qt][j] = (g < 2) ? hi : (_Float16)(qv - (float)hi);
        }
    }

    // ---- staging assignment: thread = (key sk, dim-quarter qd) ----
    const int sk = tid >> 2;
    const int qd = tid & 3;
    const float* kvp = kv + ((size_t)(b * S + sk) * (2 * HIDDEN)) + h * DHEAD + 4 * qd;
    const int ka = ksub(sk) * 512 + (qd >> 1) * 256 + kirow(sk) * 16 + (qd & 1) * 8;
    i32x4 vaddr;
    #pragma unroll
    for (int i = 0; i < 4; ++i) {
        const int d = 4 * qd + i;
        vaddr[i] = 2048 + d * 128 + (((sk >> 3) * 16) ^ ((d & 7) << 4)) + (sk & 7) * 2;
    }

    f32x4 acc[QPB];
    float m[QPB], lsum[QPB];                    // lsum = per-lane partial (16 keys)
    #pragma unroll
    for (int qt = 0; qt < QPB; ++qt) {
        acc[qt] = (f32x4){0.f, 0.f, 0.f, 0.f};
        m[qt] = -1e30f; lsum[qt] = 0.f;
    }

    const int ntiles = (kend - kstart + KBLK - 1) >> 6;

    // ---- prologue: stage tile 0 ----
    {
        const float* kp = kvp + (size_t)kstart * (2 * HIDDEN);
        f32x4 kvec = *(const f32x4*)kp;
        f32x4 vvec = *(const f32x4*)(kp + HIDDEN);
        cvt_store(&Stg[0][0], ka, vaddr, kvec, vvec);
    }
    __syncthreads();

    for (int ti = 0; ti < ntiles; ++ti) {
        const int kb = kstart + ti * KBLK;
        const char* Sb = &Stg[ti & 1][0];
        const bool hasnext = (ti + 1) < ntiles;

        // ---- T14: issue next tile's global loads before compute ----
        f32x4 nkv, nvv;
        if (hasnext) {
            const float* kp = kvp + (size_t)(kb + KBLK) * (2 * HIDDEN);
            nkv = *(const f32x4*)kp;
            nvv = *(const f32x4*)(kp + HIDDEN);
        }

        // ---- K/V fragments: read once, reused by both q-streams ----
        f16x8 kf[4];
        #pragma unroll
        for (int sub = 0; sub < 4; ++sub)
            kf[sub] = *(const f16x8*)(Sb + sub * 512 + (g & 1) * 256 + lr * 16);
        f16x8 vb0 = *(const f16x8*)(Sb + 2048 + lr * 128 + ((g * 16) ^ sw));
        f16x8 vb1 = *(const f16x8*)(Sb + 2048 + lr * 128 + ((64 + g * 16) ^ sw));

        const bool bnd = (kb + KBLK > kend);

        // ---- phase 1: QK^T for BOTH q-streams (8 independent MFMAs) ----
        // swapped+permuted: A slots [k|k], B slots [qh|ql] -> s = k*(qh+ql)
        f32x4 s[QPB][4];
        __builtin_amdgcn_s_setprio(1);
        #pragma unroll
        for (int qt = 0; qt < QPB; ++qt)
            #pragma unroll
            for (int sub = 0; sub < 4; ++sub) {
                f32x4 z = {0.f, 0.f, 0.f, 0.f};
                s[qt][sub] = __builtin_amdgcn_mfma_f32_16x16x32_f16(kf[sub], qf[qt], z, 0, 0, 0);
            }
        __builtin_amdgcn_s_setprio(0);

        if (bnd) {
            #pragma unroll
            for (int qt = 0; qt < QPB; ++qt)
                #pragma unroll
                for (int sub = 0; sub < 4; ++sub) {
                    const int kb2 = kb + (sub >> 1) * 32 + (sub & 1) * 4 + g * 8;
                    #pragma unroll
                    for (int r = 0; r < 4; ++r)
                        if (kb2 + r >= kend) s[qt][sub][r] = -1e30f;
                }
        }

        // ---- phase 2: softmax for BOTH streams (independent chains interleave) ----
        f16x8 pa[QPB][2];
        #pragma unroll
        for (int qt = 0; qt < QPB; ++qt) {
            float t0 = fmaxf(fmaxf(s[qt][0][0], s[qt][0][1]), fmaxf(s[qt][0][2], s[qt][0][3]));
            float t1 = fmaxf(fmaxf(s[qt][1][0], s[qt][1][1]), fmaxf(s[qt][1][2], s[qt][1][3]));
            float t2 = fmaxf(fmaxf(s[qt][2][0], s[qt][2][1]), fmaxf(s[qt][2][2], s[qt][2][3]));
            float t3 = fmaxf(fmaxf(s[qt][3][0], s[qt][3][1]), fmaxf(s[qt][3][2], s[qt][3][3]));
            float tmax = fmaxf(fmaxf(t0, t1), fmaxf(t2, t3));
            tmax = fmaxf(tmax, __shfl_xor(tmax, 16));
            tmax = fmaxf(tmax, __shfl_xor(tmax, 32));

            const float mn = fmaxf(m[qt], tmax);
            const float alpha = exp2f(m[qt] - mn);
            m[qt] = mn;

            float rsum = 0.f;
            #pragma unroll
            for (int sub = 0; sub < 4; ++sub)
                #pragma unroll
                for (int r = 0; r < 4; ++r) {
                    float p = exp2f(s[qt][sub][r] - mn);
                    rsum += p;
                    pa[qt][sub >> 1][(sub & 1) * 4 + r] = (_Float16)p;
                }
            lsum[qt] = lsum[qt] * alpha + rsum;   // per-lane; reduced once in epilogue
            acc[qt] *= alpha;
        }

        // ---- phase 3: PV for BOTH streams (2 independent chains of 2) ----
        __builtin_amdgcn_s_setprio(1);
        #pragma unroll
        for (int qt = 0; qt < QPB; ++qt) {
            acc[qt] = __builtin_amdgcn_mfma_f32_16x16x32_f16(vb0, pa[qt][0], acc[qt], 0, 0, 0);
            acc[qt] = __builtin_amdgcn_mfma_f32_16x16x32_f16(vb1, pa[qt][1], acc[qt], 0, 0, 0);
        }
        __builtin_amdgcn_s_setprio(0);

        // ---- T14 completion: convert + ds_write next tile, then one barrier ----
        if (hasnext)
            cvt_store(&Stg[(ti + 1) & 1][0], ka, vaddr, nkv, nvv);
        __syncthreads();
    }

    // ---- epilogue: lsum reduce once; store (m, lsum in base-2 units) ----
    #pragma unroll
    for (int qt = 0; qt < QPB; ++qt) {
        lsum[qt] += __shfl_xor(lsum[qt], 16);
        lsum[qt] += __shfl_xor(lsum[qt], 32);
        const int qglob = qrowb + qt * KBLK;
        if (SPLIT) {
            const size_t row = (((size_t)b * nc + c0) * S + qglob) * NHEAD + h;
            f16x4 pk;
            #pragma unroll
            for (int r = 0; r < 4; ++r) pk[r] = (_Float16)acc[qt][r];
            *(f16x4*)&pbuf[row * DHEAD + g * 4] = pk;
            if (g == 0) { f32x2 ml = {m[qt], lsum[qt]}; *(f32x2*)&mlbuf[row * 2] = ml; }
        } else {
            const float inv = 1.0f / lsum[qt];
            *(f32x4*)&out[((size_t)b * S + qglob) * HIDDEN + h * DHEAD + g * 4] = acc[qt] * inv;
        }
    }
}

__global__ __launch_bounds__(256)
void mha_merge(const _Float16* __restrict__ pbuf, const float* __restrict__ mlbuf,
               const int* __restrict__ seq_len, float* __restrict__ out,
               int S, int nc, int chunk)
{
    const int t = blockIdx.x * 256 + threadIdx.x;   // (b, q, h), h fastest
    const int h = t & (NHEAD - 1);
    const int rest = t >> 3;
    const int qg = rest % S;
    const int b  = rest / S;
    const int L  = seq_len[b];
    const int nch = min(nc, (L + chunk - 1) / chunk);

    const size_t cstr = (size_t)S * NHEAD;
    const size_t row0 = ((size_t)b * nc) * cstr + (size_t)qg * NHEAD + h;

    float mv[8], lv[8];
    float M = -1e30f;
    for (int c = 0; c < nch; ++c) {
        f32x2 ml = *(const f32x2*)&mlbuf[(row0 + c * cstr) * 2];
        mv[c] = ml[0]; lv[c] = ml[1];
        M = fmaxf(M, ml[0]);
    }
    float den = 0.f;
    float o[16];
    #pragma unroll
    for (int i = 0; i < 16; ++i) o[i] = 0.f;
    for (int c = 0; c < nch; ++c) {
        float w = exp2f(mv[c] - M);                 // base-2 m
        den += w * lv[c];
        const _Float16* pp = &pbuf[(row0 + c * cstr) * DHEAD];
        f16x8 p0 = *(const f16x8*)&pp[0];
        f16x8 p1 = *(const f16x8*)&pp[8];
        #pragma unroll
        for (int i = 0; i < 8; ++i) {
            o[i]     += w * (float)p0[i];
            o[i + 8] += w * (float)p1[i];
        }
    }
    const float inv = 1.0f / den;
    float* op = &out[((size_t)b * S + qg) * HIDDEN + h * DHEAD];
    #pragma unroll
    for (int i = 0; i < 4; ++i) {
        f32x4 v = {o[4*i] * inv, o[4*i+1] * inv, o[4*i+2] * inv, o[4*i+3] * inv};
        *(f32x4*)&op[4 * i] = v;
    }
}

extern "C" void kernel_launch(void* const* d_in, const int* in_sizes, int n_in,
                              void* d_out, int out_size, void* d_ws, size_t ws_size,
                              hipStream_t stream)
{
    const float* kv      = (const float*)d_in[0];
    const float* query   = (const float*)d_in[1];
    const int*   seq_len = (const int*)d_in[2];
    float* out           = (float*)d_out;

    const int B = in_sizes[2];
    const int S = in_sizes[1] / (B * HIDDEN);

    const int chunk = 512;
    const int nc = (S + chunk - 1) / chunk;
    const size_t mlb = (size_t)B * nc * S * NHEAD * 2 * sizeof(float);
    const size_t pbb = (size_t)B * nc * S * NHEAD * DHEAD * sizeof(_Float16);

    if (nc <= 8 && ws_size >= mlb + pbb) {
        float* mlbuf = (float*)d_ws;
        _Float16* pbuf = (_Float16*)((char*)d_ws + mlb);
        mha_fwd<true><<<dim3(S / (QPB * KBLK), NHEAD, B * nc), dim3(256), 0, stream>>>(
            kv, query, seq_len, nullptr, pbuf, mlbuf, S, nc, chunk);
        const int nrows = B * S * NHEAD;
        mha_merge<<<dim3((nrows + 255) / 256), dim3(256), 0, stream>>>(
            pbuf, mlbuf, seq_len, out, S, nc, chunk);
    } else {
        mha_fwd<false><<<dim3(S / (QPB * KBLK), NHEAD, B), dim3(256), 0, stream>>>(
            kv, query, seq_len, out, nullptr, nullptr, S, 1, S);
    }
}